// Round 3
// baseline (67640.948 us; speedup 1.0000x reference)
//
#include <hip/hip_runtime.h>
#include <cstdio>

#define NROWS 8640      // D*T sequential steps
#define HDIM  1024
#define NWG   64        // persistent workgroups (64 << 256 CUs -> co-resident)
#define NWAVE 16        // waves per WG; 1 h-row per wave
#define LINE_W 32       // floats per WG per publish buffer (16 chunks x 8B = one 128B line)

typedef float vf4 __attribute__((ext_vector_type(4)));
typedef float vf2 __attribute__((ext_vector_type(2)));

__device__ __forceinline__ float fsig(float x)  { return 1.f / (1.f + __expf(-x)); }
__device__ __forceinline__ float ftanh(float x) { return 2.f / (1.f + __expf(-2.f * x)) - 1.f; }

__device__ __forceinline__ float dot4(vf4 a, vf4 b) {
  return a.x*b.x + a.y*b.y + a.z*b.z + a.w*b.w;
}

// full-wave butterfly sum (xor-only: measured 0 bank conflicts previously)
#define WRED(x) { x += __shfl_xor(x,32,64); x += __shfl_xor(x,16,64); \
                  x += __shfl_xor(x, 8,64); x += __shfl_xor(x, 4,64); \
                  x += __shfl_xor(x, 2,64); x += __shfl_xor(x, 1,64); }

// ---- LLC-coherent publish/poll primitives (sc0 sc1: coherence point = Infinity Cache) ----
// SAFETY: load + s_waitcnt vmcnt(0) live in ONE asm block, so the load fully completes
// before the output register is visible to C code. No load ever outlives its variable
// (the round-2 pipelined poll violated this: a stale in-flight load clobbered a
// reallocated VGPR -> page fault).
__device__ __forceinline__ void llc_store_f2(float* p, vf2 v) {
  asm volatile("global_store_dwordx2 %0, %1, off sc0 sc1" :: "v"(p), "v"(v) : "memory");
}
__device__ __forceinline__ vf2 llc_load_f2(const float* p) {
  vf2 v;
  asm volatile("global_load_dwordx2 %0, %1, off sc0 sc1\n\ts_waitcnt vmcnt(0)"
               : "=&v"(v) : "v"(p) : "memory");
  return v;
}

// 64 WGs x 1024 threads (16 waves). WG g owns h-rows [16g,16g+16); wave w owns row
// 16g+w of all 5 matrices. w_t/w_oh/w_ih fragments live in VGPRs (12 vf4 = 48 regs,
// lane l covers h-cols {4l..4l+3}+256m); w_gh/w_fo slices live in LDS (128 KB) so the
// whole working set fits the 128-VGPR cap of a 16-wave block -> no spills.
// Per phase each wave publishes {value, seq} as one 8B chunk; thread t polls chunk t
// (= h-row t) and scatters 1 float into the double-buffered h_sh. 2 barriers/step.
__global__ __launch_bounds__(1024, 4) void scan_kernel(
    const float* __restrict__ pre_ho, const float* __restrict__ pre_i,
    const float* __restrict__ pre_g,  const float* __restrict__ pre_f,
    const float* __restrict__ pre_o,
    const float* __restrict__ w_t,  const float* __restrict__ w_ih,
    const float* __restrict__ w_gh, const float* __restrict__ w_fo,
    const float* __restrict__ w_oh,
    float* __restrict__ lines0, float* __restrict__ lines1,
    float* __restrict__ hs, float* __restrict__ cs)
{
  __shared__ __align__(16) float h_sh[2][HDIM];          // [0]=h, [1]=h_o
  __shared__ __align__(16) float wgh_sh[NWAVE * HDIM];   // 64 KB
  __shared__ __align__(16) float wfo_sh[NWAVE * HDIM];   // 64 KB

  const int tid  = threadIdx.x;
  const int lane = tid & 63;
  const int w    = tid >> 6;            // wave 0..15
  const int wg   = blockIdx.x;
  const int row  = wg * NWAVE + w;      // this wave's h-row

  for (int i = tid; i < HDIM; i += 1024) { h_sh[0][i] = 0.f; h_sh[1][i] = 0.f; }
  {
    const float* gsrc = w_gh + (long)wg * NWAVE * HDIM;
    const float* fsrc = w_fo + (long)wg * NWAVE * HDIM;
    for (int i = 4 * tid; i < NWAVE * HDIM; i += 4096) {
      *(vf4*)(wgh_sh + i) = *(const vf4*)(gsrc + i);
      *(vf4*)(wfo_sh + i) = *(const vf4*)(fsrc + i);
    }
  }

  // VGPR weight fragments: 4 vf4 per matrix
  vf4 Wt[4], Woh[4], Wih[4];
#pragma unroll
  for (int m = 0; m < 4; ++m) {
    Wt[m]  = *(const vf4*)(w_t  + (long)row * HDIM + m * 256 + 4 * lane);
    Woh[m] = *(const vf4*)(w_oh + (long)row * HDIM + m * 256 + 4 * lane);
    Wih[m] = *(const vf4*)(w_ih + (long)row * HDIM + m * 256 + 4 * lane);
  }

  // per-row state, kept wave-uniform (all lanes see the butterfly-summed result)
  float cprev = 0.f, oo = 0.f;
  float ph = pre_ho[row], po = pre_o[row];
  float pi = pre_i[row],  pg = pre_g[row], pf = pre_f[row];

  const float* pollA = lines0 + 2 * tid;   // chunk t <-> h-row t
  const float* pollB = lines1 + 2 * tid;
  float* pubA = lines0 + 2 * row;
  float* pubB = lines1 + 2 * row;

  __syncthreads();

  for (int n = 0; n < NROWS; ++n) {
    const int tgtA = 2 * n + 1, tgtB = 2 * n + 2;

    // ==== phase A: h_o = sig(ph + 2*W_t h_prev), o = sig(po + W_oh h_prev) ====
    {
      vf4 h0 = *(const vf4*)(h_sh[0] + 4 * lane);
      vf4 h1 = *(const vf4*)(h_sh[0] + 4 * lane + 256);
      vf4 h2 = *(const vf4*)(h_sh[0] + 4 * lane + 512);
      vf4 h3 = *(const vf4*)(h_sh[0] + 4 * lane + 768);
      float t = dot4(Wt[0], h0) + dot4(Wt[1], h1) + dot4(Wt[2], h2) + dot4(Wt[3], h3);
      float o = dot4(Woh[0],h0) + dot4(Woh[1],h1) + dot4(Woh[2],h2) + dot4(Woh[3],h3);
      WRED(t); WRED(o);
      float hov = fsig(ph + 2.f * t);
      oo = fsig(po + o);
      if (lane == 0) {
        vf2 d; d.x = hov; d.y = __int_as_float(tgtA);
        llc_store_f2(pubA, d);
      }
      vf2 d;
      do { d = llc_load_f2(pollA); } while (__float_as_int(d.y) < tgtA);
      h_sh[1][tid] = d.x;                  // h_o into buffer 1
      __syncthreads();
    }

    // ==== phase B: gates from h_o; c,h update ====
    {
      // prefetch next step's pre_* early (overlaps dot compute)
      float ph2 = 0.f, po2 = 0.f, pi2 = 0.f, pg2 = 0.f, pf2 = 0.f;
      if (n + 1 < NROWS) {
        long o2 = (long)(n + 1) * HDIM + row;
        ph2 = pre_ho[o2]; po2 = pre_o[o2];
        pi2 = pre_i[o2];  pg2 = pre_g[o2]; pf2 = pre_f[o2];
      }
      vf4 h0 = *(const vf4*)(h_sh[1] + 4 * lane);
      vf4 h1 = *(const vf4*)(h_sh[1] + 4 * lane + 256);
      vf4 h2 = *(const vf4*)(h_sh[1] + 4 * lane + 512);
      vf4 h3 = *(const vf4*)(h_sh[1] + 4 * lane + 768);
      const float* gp = wgh_sh + w * HDIM + 4 * lane;
      const float* fp = wfo_sh + w * HDIM + 4 * lane;
      float i_ = dot4(Wih[0], h0) + dot4(Wih[1], h1) + dot4(Wih[2], h2) + dot4(Wih[3], h3);
      float g_ = dot4(*(const vf4*)(gp      ), h0) + dot4(*(const vf4*)(gp + 256), h1)
               + dot4(*(const vf4*)(gp + 512), h2) + dot4(*(const vf4*)(gp + 768), h3);
      float f_ = dot4(*(const vf4*)(fp      ), h0) + dot4(*(const vf4*)(fp + 256), h1)
               + dot4(*(const vf4*)(fp + 512), h2) + dot4(*(const vf4*)(fp + 768), h3);
      WRED(i_); WRED(g_); WRED(f_);
      float ii = fsig(pi + i_);
      float gg = ftanh(pg + g_);
      float ff = fsig(pf + f_);
      float cc = ff * cprev + ii * gg;
      float hh = oo * ftanh(cc);
      cprev = cc;
      if (lane == 0) {
        vf2 d; d.x = hh; d.y = __int_as_float(tgtB);
        llc_store_f2(pubB, d);             // publish first: earliest visibility
        hs[(long)n * HDIM + row] = hh;
        cs[(long)n * HDIM + row] = cc;
      }
      ph = ph2; po = po2; pi = pi2; pg = pg2; pf = pf2;
      if (n + 1 < NROWS) {                 // last step: nobody needs h -> skip poll
        vf2 d;
        do { d = llc_load_f2(pollB); } while (__float_as_int(d.y) < tgtB);
        h_sh[0][tid] = d.x;                // new h into buffer 0
      }
      __syncthreads();
    }
  }
}

// ---------- generic accumulating GEMM: C[n,h] += sum_k A[rowmap(n),k]*B[h,k] ----------
__global__ __launch_bounds__(256) void gemm_acc(
    float* __restrict__ C, const float* __restrict__ A, const float* __restrict__ B,
    int K, int shift, int minn)
{
  __shared__ float Asf[16 * 68];
  __shared__ float Bsf[16 * 68];
  const int tid = threadIdx.x;
  const int h0  = blockIdx.x * 64;
  const int n0  = blockIdx.y * 64;
  const int r   = tid >> 2;
  const int kq  = (tid & 3) << 2;
  const int tx  = tid & 15, ty = tid >> 4;

  int arow = n0 + r;
  int src  = arow - shift; if (src < 0) src += NROWS;
  const bool avalid = (arow >= minn);
  const float* Ap = A + (long)src * K + kq;
  const float* Bp = B + (long)(h0 + r) * K + kq;

  vf4 acc0 = {0.f,0.f,0.f,0.f}, acc1 = {0.f,0.f,0.f,0.f};
  vf4 acc2 = {0.f,0.f,0.f,0.f}, acc3 = {0.f,0.f,0.f,0.f};
  const vf4 zero = {0.f,0.f,0.f,0.f};

  for (int k0 = 0; k0 < K; k0 += 16) {
    vf4 av = avalid ? *(const vf4*)(Ap + k0) : zero;
    vf4 bv = *(const vf4*)(Bp + k0);
    __syncthreads();
    Asf[(kq+0)*68 + r] = av.x;  Asf[(kq+1)*68 + r] = av.y;
    Asf[(kq+2)*68 + r] = av.z;  Asf[(kq+3)*68 + r] = av.w;
    Bsf[(kq+0)*68 + r] = bv.x;  Bsf[(kq+1)*68 + r] = bv.y;
    Bsf[(kq+2)*68 + r] = bv.z;  Bsf[(kq+3)*68 + r] = bv.w;
    __syncthreads();
#pragma unroll
    for (int c = 0; c < 16; ++c) {
      vf4 a = *(const vf4*)(Asf + c*68 + (ty << 2));
      vf4 b = *(const vf4*)(Bsf + c*68 + (tx << 2));
      acc0 += a.x * b;
      acc1 += a.y * b;
      acc2 += a.z * b;
      acc3 += a.w * b;
    }
  }
  float* cp = C + (long)(n0 + (ty << 2)) * HDIM + h0 + (tx << 2);
  { vf4 t = *(vf4*)(cp + 0*HDIM); t += acc0; *(vf4*)(cp + 0*HDIM) = t; }
  { vf4 t = *(vf4*)(cp + 1*HDIM); t += acc1; *(vf4*)(cp + 1*HDIM) = t; }
  { vf4 t = *(vf4*)(cp + 2*HDIM); t += acc2; *(vf4*)(cp + 2*HDIM) = t; }
  { vf4 t = *(vf4*)(cp + 3*HDIM); t += acc3; *(vf4*)(cp + 3*HDIM) = t; }
}

__global__ void bias_init(float* __restrict__ out, const float* __restrict__ bias) {
  int i = blockIdx.x * blockDim.x + threadIdx.x;
  vf4 v = {0.f,0.f,0.f,0.f};
  if (bias) { int h = (i << 2) & (HDIM - 1); v = *(const vf4*)(bias + h); }
  *((vf4*)out + i) = v;
}

__global__ void sigmoid_k(float* __restrict__ e) {
  int i = blockIdx.x * blockDim.x + threadIdx.x;
  vf4 v = *((vf4*)e + i);
  v.x = fsig(v.x); v.y = fsig(v.y); v.z = fsig(v.z); v.w = fsig(v.w);
  *((vf4*)e + i) = v;
}

extern "C" void kernel_launch(void* const* d_in, const int* in_sizes, int n_in,
                              void* d_out, int out_size, void* d_ws, size_t ws_size,
                              hipStream_t stream) {
  const float* x    = (const float*)d_in[0];
  const float* xw   = (const float*)d_in[1];
  const float* w_ix = (const float*)d_in[2];
  const float* w_ih = (const float*)d_in[3];
  const float* w_ie = (const float*)d_in[4];
  const float* b_i  = (const float*)d_in[5];
  const float* w_fx = (const float*)d_in[6];
  const float* w_fo = (const float*)d_in[7];
  const float* w_fe = (const float*)d_in[8];
  const float* b_f  = (const float*)d_in[9];
  const float* w_ox = (const float*)d_in[10];
  const float* w_oh = (const float*)d_in[11];
  const float* w_oe = (const float*)d_in[12];
  const float* b_o  = (const float*)d_in[13];
  const float* w_gx = (const float*)d_in[14];
  const float* w_gh = (const float*)d_in[15];
  const float* b_g  = (const float*)d_in[16];
  const float* w_d  = (const float*)d_in[17];
  const float* w_w  = (const float*)d_in[18];
  const float* w_m  = (const float*)d_in[19];
  const float* w_t  = (const float*)d_in[20];
  const float* w_e  = (const float*)d_in[21];
  const float* b_e  = (const float*)d_in[22];

  const long S = (long)NROWS * HDIM;
  float* ws_f   = (float*)d_ws;
  float* pre_ho = ws_f + 0*S;
  float* pre_i  = ws_f + 1*S;
  float* pre_g  = ws_f + 2*S;
  float* pre_f  = ws_f + 3*S;
  float* pre_o  = ws_f + 4*S;
  float* e_buf  = ws_f + 5*S;
  float* lines0 = ws_f + 6*S;
  float* lines1 = lines0 + NWG*LINE_W;

  size_t need = (size_t)(6*S + 2*NWG*LINE_W) * sizeof(float);
  if (ws_size < need) {
    fprintf(stderr, "kernel_launch: ws too small (have %zu, need %zu)\n", ws_size, need);
    return;
  }

  dim3 ggrid(HDIM/64, NROWS/64);

  bias_init<<<NROWS, 256, 0, stream>>>(pre_i, b_i);
  bias_init<<<NROWS, 256, 0, stream>>>(pre_g, b_g);
  bias_init<<<NROWS, 256, 0, stream>>>(pre_f, b_f);
  bias_init<<<NROWS, 256, 0, stream>>>(pre_o, b_o);
  bias_init<<<NROWS, 256, 0, stream>>>(e_buf, b_e);
  bias_init<<<NROWS, 256, 0, stream>>>(pre_ho, nullptr);

  gemm_acc<<<ggrid, 256, 0, stream>>>(e_buf, xw, w_e, 64, 0, 0);
  sigmoid_k<<<NROWS, 256, 0, stream>>>(e_buf);

  gemm_acc<<<ggrid, 256, 0, stream>>>(pre_i, x, w_ix, 512, 0, 0);
  gemm_acc<<<ggrid, 256, 0, stream>>>(pre_g, x, w_gx, 512, 0, 0);
  gemm_acc<<<ggrid, 256, 0, stream>>>(pre_f, x, w_fx, 512, 0, 0);
  gemm_acc<<<ggrid, 256, 0, stream>>>(pre_o, x, w_ox, 512, 0, 0);
  gemm_acc<<<ggrid, 256, 0, stream>>>(pre_i, e_buf, w_ie, 1024, 0, 0);
  gemm_acc<<<ggrid, 256, 0, stream>>>(pre_f, e_buf, w_fe, 1024, 0, 0);
  gemm_acc<<<ggrid, 256, 0, stream>>>(pre_o, e_buf, w_oe, 1024, 0, 0);
  gemm_acc<<<ggrid, 256, 0, stream>>>(pre_ho, x, w_d, 512,   96,   96);
  gemm_acc<<<ggrid, 256, 0, stream>>>(pre_ho, x, w_w, 512,  576,  672);
  gemm_acc<<<ggrid, 256, 0, stream>>>(pre_ho, x, w_m, 512, 2784, 2688);

  hipMemsetAsync(lines0, 0, 2 * NWG * LINE_W * sizeof(float), stream);

  float* hs = (float*)d_out;
  float* cs = hs + S;
  scan_kernel<<<NWG, 1024, 0, stream>>>(pre_ho, pre_i, pre_g, pre_f, pre_o,
                                        w_t, w_ih, w_gh, w_fo, w_oh,
                                        lines0, lines1, hs, cs);
}

// Round 4
// 56148.718 us; speedup vs baseline: 1.2047x; 1.2047x over previous
//
#include <hip/hip_runtime.h>
#include <cstdio>

#define NROWS 8640      // D*T sequential steps
#define HDIM  1024
#define NWG   64        // persistent workgroups (1 per CU, 64 << 256 CUs -> co-resident)
#define RPW   16        // rows per WG
#define LINE_W 32       // floats per WG per publish buffer (8 chunks x 16B = one 128B line)

typedef float vf4 __attribute__((ext_vector_type(4)));

__device__ __forceinline__ float fsig(float x)  { return 1.f / (1.f + __expf(-x)); }
__device__ __forceinline__ float ftanh(float x) { return 2.f / (1.f + __expf(-2.f * x)) - 1.f; }

__device__ __forceinline__ float dot4(vf4 a, vf4 b) {
  return a.x*b.x + a.y*b.y + a.z*b.z + a.w*b.w;
}

// full-wave butterfly sum
#define WRED(x) { x += __shfl_xor(x,32,64); x += __shfl_xor(x,16,64); \
                  x += __shfl_xor(x, 8,64); x += __shfl_xor(x, 4,64); \
                  x += __shfl_xor(x, 2,64); x += __shfl_xor(x, 1,64); }

// ---- LLC-coherent 16B ops (sc0 sc1: bypass non-coherent per-XCD L1/L2) ----
// SAFETY: load + s_waitcnt vmcnt(0) in ONE asm block -> no load outlives its variable.
__device__ __forceinline__ vf4 llc_load_f4(const float* p) {
  vf4 v;
  asm volatile("global_load_dwordx4 %0, %1, off sc0 sc1\n\ts_waitcnt vmcnt(0)"
               : "=&v"(v) : "v"(p) : "memory");
  return v;
}
__device__ __forceinline__ void llc_store_f4(float* p, vf4 v) {
  asm volatile("global_store_dwordx4 %0, %1, off sc0 sc1" :: "v"(p), "v"(v) : "memory");
}

// Opaque weight load: an asm result CANNOT be rematerialized by the compiler, so
// the 40 weight fragments stay RESIDENT in VGPRs for the whole scan (rocprof r0/r3
// showed VGPR_Count 108/60 -> compiler was re-loading weights every phase on the
// post-barrier critical path). Plain cached load (read-only data, no sc flags).
__device__ __forceinline__ vf4 opaque_load_f4(const float* p) {
  vf4 v;
  asm volatile("global_load_dwordx4 %0, %1, off\n\ts_waitcnt vmcnt(0)"
               : "=&v"(v) : "v"(p));
  return v;
}

// 64 WGs x 512 threads (8 waves). WG g owns rows [16g,16g+16); wave w owns rows
// 16g+2w, 16g+2w+1 of all 5 matrices; weights pinned in VGPRs via opaque loads
// (lane l covers h-columns {4l..4l+3} + 256m, m=0..3; 40 vf4 = 160 VGPRs, cap 256
// at __launch_bounds__(512,2); only 1 WG/CU anyway since 64 WGs on 256 CUs).
// Per phase each wave publishes its 2 results as one 16B chunk [v0 v1 seq pad];
// thread t polls chunk (srcWG=t>>3, srcWave=t&7) and scatters 2 floats into the
// double-buffered h_sh (A: buf0->buf1, B: buf1->buf0) -> only 2 barriers/step.
__global__ __launch_bounds__(512, 2) void scan_kernel(
    const float* __restrict__ pre_ho, const float* __restrict__ pre_i,
    const float* __restrict__ pre_g,  const float* __restrict__ pre_f,
    const float* __restrict__ pre_o,
    const float* __restrict__ w_t,  const float* __restrict__ w_ih,
    const float* __restrict__ w_gh, const float* __restrict__ w_fo,
    const float* __restrict__ w_oh,
    float* __restrict__ lines0, float* __restrict__ lines1,
    float* __restrict__ hs, float* __restrict__ cs)
{
  __shared__ __align__(16) float h_sh[2][HDIM];   // [0]=h, [1]=h_o

  const int tid  = threadIdx.x;
  const int lane = tid & 63;
  const int w    = tid >> 6;          // wave 0..7
  const int wg   = blockIdx.x;
  const int r0   = wg * RPW + 2 * w;  // this wave's first row
  const int myrow = r0 + lane;        // valid for lane<2

  for (int i = tid; i < HDIM; i += 512) { h_sh[0][i] = 0.f; h_sh[1][i] = 0.f; }

  // weight fragments: Wf[mat][row][m]; mat: 0=w_t 1=w_oh 2=w_ih 3=w_gh 4=w_fo
  // Fully unrolled so every Wf index is compile-time constant (rule #20).
  vf4 Wf[5][2][4];
  {
    const float* Wp[5] = { w_t, w_oh, w_ih, w_gh, w_fo };
#pragma unroll
    for (int mt = 0; mt < 5; ++mt)
#pragma unroll
      for (int rr = 0; rr < 2; ++rr)
#pragma unroll
        for (int m = 0; m < 4; ++m)
          Wf[mt][rr][m] = opaque_load_f4(Wp[mt] + (long)(r0+rr)*HDIM + m*256 + 4*lane);
  }

  // per-row state in lanes 0,1 of the owning wave
  float cprev = 0.f, oo = 0.f;
  float ph = 0.f, po = 0.f, pi = 0.f, pg = 0.f, pf = 0.f;
  if (lane < 2) {
    ph = pre_ho[myrow]; po = pre_o[myrow];
    pi = pre_i[myrow];  pg = pre_g[myrow]; pf = pre_f[myrow];
  }

  // poll assignment: thread t polls chunk (srcWG = t>>3, srcWave = t&7)
  const long pofs = (long)(tid >> 3) * LINE_W + (long)(tid & 7) * 4;
  const int  dsh  = 2 * tid;          // h_sh scatter base = srcWG*16 + srcWave*2
  const float* pollA = lines0 + pofs;
  const float* pollB = lines1 + pofs;
  float* pubA = lines0 + (long)wg * LINE_W + (long)w * 4;
  float* pubB = lines1 + (long)wg * LINE_W + (long)w * 4;

  __syncthreads();

  for (int n = 0; n < NROWS; ++n) {
    const int tgtA = 2*n + 1, tgtB = 2*n + 2;

    // ======== phase A: h_o = sig(ph + 2*W_t h_prev), o = sig(po + W_oh h_prev) ====
    {
      vf4 h0 = *(const vf4*)(h_sh[0] + 4*lane);
      vf4 h1 = *(const vf4*)(h_sh[0] + 4*lane + 256);
      vf4 h2 = *(const vf4*)(h_sh[0] + 4*lane + 512);
      vf4 h3 = *(const vf4*)(h_sh[0] + 4*lane + 768);
      float t0 = dot4(Wf[0][0][0],h0)+dot4(Wf[0][0][1],h1)+dot4(Wf[0][0][2],h2)+dot4(Wf[0][0][3],h3);
      float t1 = dot4(Wf[0][1][0],h0)+dot4(Wf[0][1][1],h1)+dot4(Wf[0][1][2],h2)+dot4(Wf[0][1][3],h3);
      float o0 = dot4(Wf[1][0][0],h0)+dot4(Wf[1][0][1],h1)+dot4(Wf[1][0][2],h2)+dot4(Wf[1][0][3],h3);
      float o1 = dot4(Wf[1][1][0],h0)+dot4(Wf[1][1][1],h1)+dot4(Wf[1][1][2],h2)+dot4(Wf[1][1][3],h3);
      WRED(t0); WRED(t1); WRED(o0); WRED(o1);
      float hov = 0.f;
      if (lane < 2) {
        float ut = lane ? t1 : t0;
        float uo = lane ? o1 : o0;
        hov = fsig(ph + 2.f * ut);
        oo  = fsig(po + uo);
      }
      float hon = __shfl_xor(hov, 1, 64);   // lane0 gets lane1's value
      if (lane == 0) {
        vf4 d; d.x = hov; d.y = hon; d.z = __int_as_float(tgtA); d.w = 0.f;
        llc_store_f4(pubA, d);
      }
      vf4 d;
      do { d = llc_load_f4(pollA); } while (__float_as_int(d.z) < tgtA);
      *(float2*)(h_sh[1] + dsh) = make_float2(d.x, d.y);   // h_o into buffer 1
      __syncthreads();
    }

    // ======== phase B: gates from h_o; c,h update ========
    {
      // prefetch next step's pre_* early (overlaps dot compute)
      float ph2 = 0.f, po2 = 0.f, pi2 = 0.f, pg2 = 0.f, pf2 = 0.f;
      if (lane < 2 && n + 1 < NROWS) {
        long o2 = (long)(n+1)*HDIM + myrow;
        ph2 = pre_ho[o2]; po2 = pre_o[o2];
        pi2 = pre_i[o2];  pg2 = pre_g[o2]; pf2 = pre_f[o2];
      }
      vf4 h0 = *(const vf4*)(h_sh[1] + 4*lane);
      vf4 h1 = *(const vf4*)(h_sh[1] + 4*lane + 256);
      vf4 h2 = *(const vf4*)(h_sh[1] + 4*lane + 512);
      vf4 h3 = *(const vf4*)(h_sh[1] + 4*lane + 768);
      float i0 = dot4(Wf[2][0][0],h0)+dot4(Wf[2][0][1],h1)+dot4(Wf[2][0][2],h2)+dot4(Wf[2][0][3],h3);
      float i1 = dot4(Wf[2][1][0],h0)+dot4(Wf[2][1][1],h1)+dot4(Wf[2][1][2],h2)+dot4(Wf[2][1][3],h3);
      float g0 = dot4(Wf[3][0][0],h0)+dot4(Wf[3][0][1],h1)+dot4(Wf[3][0][2],h2)+dot4(Wf[3][0][3],h3);
      float g1 = dot4(Wf[3][1][0],h0)+dot4(Wf[3][1][1],h1)+dot4(Wf[3][1][2],h2)+dot4(Wf[3][1][3],h3);
      float f0 = dot4(Wf[4][0][0],h0)+dot4(Wf[4][0][1],h1)+dot4(Wf[4][0][2],h2)+dot4(Wf[4][0][3],h3);
      float f1 = dot4(Wf[4][1][0],h0)+dot4(Wf[4][1][1],h1)+dot4(Wf[4][1][2],h2)+dot4(Wf[4][1][3],h3);
      WRED(i0); WRED(i1); WRED(g0); WRED(g1); WRED(f0); WRED(f1);
      float hhv = 0.f, ccv = 0.f;
      if (lane < 2) {
        float ui = lane ? i1 : i0;
        float ug = lane ? g1 : g0;
        float uf = lane ? f1 : f0;
        float ii = fsig(pi + ui);
        float gg = ftanh(pg + ug);
        float ff = fsig(pf + uf);
        ccv = ff * cprev + ii * gg;
        hhv = oo * ftanh(ccv);
        cprev = ccv;
      }
      float hhn = __shfl_xor(hhv, 1, 64);
      if (lane == 0) {                       // publish FIRST: earliest visibility
        vf4 d; d.x = hhv; d.y = hhn; d.z = __int_as_float(tgtB); d.w = 0.f;
        llc_store_f4(pubB, d);
      }
      if (lane < 2) {                        // output stores off the critical path
        hs[(long)n*HDIM + myrow] = hhv;
        cs[(long)n*HDIM + myrow] = ccv;
      }
      ph = ph2; po = po2; pi = pi2; pg = pg2; pf = pf2;
      if (n + 1 < NROWS) {                   // last step: nobody needs h -> skip poll
        vf4 d;
        do { d = llc_load_f4(pollB); } while (__float_as_int(d.z) < tgtB);
        *(float2*)(h_sh[0] + dsh) = make_float2(d.x, d.y); // new h into buffer 0
      }
      __syncthreads();
    }
  }
}

// ---------- generic accumulating GEMM: C[n,h] += sum_k A[rowmap(n),k]*B[h,k] ----------
__global__ __launch_bounds__(256) void gemm_acc(
    float* __restrict__ C, const float* __restrict__ A, const float* __restrict__ B,
    int K, int shift, int minn)
{
  __shared__ float Asf[16 * 68];
  __shared__ float Bsf[16 * 68];
  const int tid = threadIdx.x;
  const int h0  = blockIdx.x * 64;
  const int n0  = blockIdx.y * 64;
  const int r   = tid >> 2;
  const int kq  = (tid & 3) << 2;
  const int tx  = tid & 15, ty = tid >> 4;

  int arow = n0 + r;
  int src  = arow - shift; if (src < 0) src += NROWS;
  const bool avalid = (arow >= minn);
  const float* Ap = A + (long)src * K + kq;
  const float* Bp = B + (long)(h0 + r) * K + kq;

  vf4 acc0 = {0.f,0.f,0.f,0.f}, acc1 = {0.f,0.f,0.f,0.f};
  vf4 acc2 = {0.f,0.f,0.f,0.f}, acc3 = {0.f,0.f,0.f,0.f};
  const vf4 zero = {0.f,0.f,0.f,0.f};

  for (int k0 = 0; k0 < K; k0 += 16) {
    vf4 av = avalid ? *(const vf4*)(Ap + k0) : zero;
    vf4 bv = *(const vf4*)(Bp + k0);
    __syncthreads();
    Asf[(kq+0)*68 + r] = av.x;  Asf[(kq+1)*68 + r] = av.y;
    Asf[(kq+2)*68 + r] = av.z;  Asf[(kq+3)*68 + r] = av.w;
    Bsf[(kq+0)*68 + r] = bv.x;  Bsf[(kq+1)*68 + r] = bv.y;
    Bsf[(kq+2)*68 + r] = bv.z;  Bsf[(kq+3)*68 + r] = bv.w;
    __syncthreads();
#pragma unroll
    for (int c = 0; c < 16; ++c) {
      vf4 a = *(const vf4*)(Asf + c*68 + (ty << 2));
      vf4 b = *(const vf4*)(Bsf + c*68 + (tx << 2));
      acc0 += a.x * b;
      acc1 += a.y * b;
      acc2 += a.z * b;
      acc3 += a.w * b;
    }
  }
  float* cp = C + (long)(n0 + (ty << 2)) * HDIM + h0 + (tx << 2);
  { vf4 t = *(vf4*)(cp + 0*HDIM); t += acc0; *(vf4*)(cp + 0*HDIM) = t; }
  { vf4 t = *(vf4*)(cp + 1*HDIM); t += acc1; *(vf4*)(cp + 1*HDIM) = t; }
  { vf4 t = *(vf4*)(cp + 2*HDIM); t += acc2; *(vf4*)(cp + 2*HDIM) = t; }
  { vf4 t = *(vf4*)(cp + 3*HDIM); t += acc3; *(vf4*)(cp + 3*HDIM) = t; }
}

__global__ void bias_init(float* __restrict__ out, const float* __restrict__ bias) {
  int i = blockIdx.x * blockDim.x + threadIdx.x;
  vf4 v = {0.f,0.f,0.f,0.f};
  if (bias) { int h = (i << 2) & (HDIM - 1); v = *(const vf4*)(bias + h); }
  *((vf4*)out + i) = v;
}

__global__ void sigmoid_k(float* __restrict__ e) {
  int i = blockIdx.x * blockDim.x + threadIdx.x;
  vf4 v = *((vf4*)e + i);
  v.x = fsig(v.x); v.y = fsig(v.y); v.z = fsig(v.z); v.w = fsig(v.w);
  *((vf4*)e + i) = v;
}

extern "C" void kernel_launch(void* const* d_in, const int* in_sizes, int n_in,
                              void* d_out, int out_size, void* d_ws, size_t ws_size,
                              hipStream_t stream) {
  const float* x    = (const float*)d_in[0];
  const float* xw   = (const float*)d_in[1];
  const float* w_ix = (const float*)d_in[2];
  const float* w_ih = (const float*)d_in[3];
  const float* w_ie = (const float*)d_in[4];
  const float* b_i  = (const float*)d_in[5];
  const float* w_fx = (const float*)d_in[6];
  const float* w_fo = (const float*)d_in[7];
  const float* w_fe = (const float*)d_in[8];
  const float* b_f  = (const float*)d_in[9];
  const float* w_ox = (const float*)d_in[10];
  const float* w_oh = (const float*)d_in[11];
  const float* w_oe = (const float*)d_in[12];
  const float* b_o  = (const float*)d_in[13];
  const float* w_gx = (const float*)d_in[14];
  const float* w_gh = (const float*)d_in[15];
  const float* b_g  = (const float*)d_in[16];
  const float* w_d  = (const float*)d_in[17];
  const float* w_w  = (const float*)d_in[18];
  const float* w_m  = (const float*)d_in[19];
  const float* w_t  = (const float*)d_in[20];
  const float* w_e  = (const float*)d_in[21];
  const float* b_e  = (const float*)d_in[22];

  const long S = (long)NROWS * HDIM;
  float* ws_f   = (float*)d_ws;
  float* pre_ho = ws_f + 0*S;
  float* pre_i  = ws_f + 1*S;
  float* pre_g  = ws_f + 2*S;
  float* pre_f  = ws_f + 3*S;
  float* pre_o  = ws_f + 4*S;
  float* e_buf  = ws_f + 5*S;
  float* lines0 = ws_f + 6*S;
  float* lines1 = lines0 + NWG*LINE_W;

  size_t need = (size_t)(6*S + 2*NWG*LINE_W) * sizeof(float);
  if (ws_size < need) {
    fprintf(stderr, "kernel_launch: ws too small (have %zu, need %zu)\n", ws_size, need);
    return;
  }

  dim3 ggrid(HDIM/64, NROWS/64);

  bias_init<<<NROWS, 256, 0, stream>>>(pre_i, b_i);
  bias_init<<<NROWS, 256, 0, stream>>>(pre_g, b_g);
  bias_init<<<NROWS, 256, 0, stream>>>(pre_f, b_f);
  bias_init<<<NROWS, 256, 0, stream>>>(pre_o, b_o);
  bias_init<<<NROWS, 256, 0, stream>>>(e_buf, b_e);
  bias_init<<<NROWS, 256, 0, stream>>>(pre_ho, nullptr);

  gemm_acc<<<ggrid, 256, 0, stream>>>(e_buf, xw, w_e, 64, 0, 0);
  sigmoid_k<<<NROWS, 256, 0, stream>>>(e_buf);

  gemm_acc<<<ggrid, 256, 0, stream>>>(pre_i, x, w_ix, 512, 0, 0);
  gemm_acc<<<ggrid, 256, 0, stream>>>(pre_g, x, w_gx, 512, 0, 0);
  gemm_acc<<<ggrid, 256, 0, stream>>>(pre_f, x, w_fx, 512, 0, 0);
  gemm_acc<<<ggrid, 256, 0, stream>>>(pre_o, x, w_ox, 512, 0, 0);
  gemm_acc<<<ggrid, 256, 0, stream>>>(pre_i, e_buf, w_ie, 1024, 0, 0);
  gemm_acc<<<ggrid, 256, 0, stream>>>(pre_f, e_buf, w_fe, 1024, 0, 0);
  gemm_acc<<<ggrid, 256, 0, stream>>>(pre_o, e_buf, w_oe, 1024, 0, 0);
  gemm_acc<<<ggrid, 256, 0, stream>>>(pre_ho, x, w_d, 512,   96,   96);
  gemm_acc<<<ggrid, 256, 0, stream>>>(pre_ho, x, w_w, 512,  576,  672);
  gemm_acc<<<ggrid, 256, 0, stream>>>(pre_ho, x, w_m, 512, 2784, 2688);

  hipMemsetAsync(lines0, 0, 2 * NWG * LINE_W * sizeof(float), stream);

  float* hs = (float*)d_out;
  float* cs = hs + S;
  scan_kernel<<<NWG, 512, 0, stream>>>(pre_ho, pre_i, pre_g, pre_f, pre_o,
                                       w_t, w_ih, w_gh, w_fo, w_oh,
                                       lines0, lines1, hs, cs);
}

// Round 5
// 55559.570 us; speedup vs baseline: 1.2174x; 1.0106x over previous
//
#include <hip/hip_runtime.h>
#include <cstdio>

#define NROWS 8640      // D*T sequential steps (135 blocks of 64)
#define HDIM  1024
#define NWG   64        // persistent workgroups (1 per CU, 64 << 256 CUs -> co-resident)
#define RPW   16        // rows per WG
#define PBLK  64        // steps per pre/out staging block
#define LINE_W 32       // floats per WG per publish buffer (8 chunks x 16B = one 128B line)

typedef float vf4 __attribute__((ext_vector_type(4)));

__device__ __forceinline__ float fsig(float x)  { return 1.f / (1.f + __expf(-x)); }
__device__ __forceinline__ float ftanh(float x) { return 2.f / (1.f + __expf(-2.f * x)) - 1.f; }

__device__ __forceinline__ float dot4(vf4 a, vf4 b) {
  return a.x*b.x + a.y*b.y + a.z*b.z + a.w*b.w;
}

// full-wave butterfly sum
#define WRED(x) { x += __shfl_xor(x,32,64); x += __shfl_xor(x,16,64); \
                  x += __shfl_xor(x, 8,64); x += __shfl_xor(x, 4,64); \
                  x += __shfl_xor(x, 2,64); x += __shfl_xor(x, 1,64); }

// ---- LLC-coherent 16B ops (sc0 sc1: bypass non-coherent per-XCD L1/L2) ----
// SAFETY: load + s_waitcnt vmcnt(0) in ONE asm block -> no load outlives its variable.
__device__ __forceinline__ vf4 llc_load_f4(const float* p) {
  vf4 v;
  asm volatile("global_load_dwordx4 %0, %1, off sc0 sc1\n\ts_waitcnt vmcnt(0)"
               : "=&v"(v) : "v"(p) : "memory");
  return v;
}
__device__ __forceinline__ void llc_store_f4(float* p, vf4 v) {
  asm volatile("global_store_dwordx4 %0, %1, off sc0 sc1" :: "v"(p), "v"(v) : "memory");
}

// 64 WGs x 512 threads (8 waves). WG g owns rows [16g,16g+16); wave w owns rows
// 16g+2w, 16g+2w+1 of all 5 matrices (weights as plain loads, round-0 behavior:
// compiler reloads from L2 per phase -- measured cheap, weights are L2-resident).
//
// JITTER ELIMINATION (this round): pre_ho/i/g/f/o for 64 steps are block-staged
// into LDS by all 512 threads with coalesced vf4 loads (full 64B lines), so the
// per-step critical path has NO HBM-latency loads; hs/cs are batched in LDS and
// flushed coalesced once per block. Requires pre_* contiguous at stride S in ws
// (guaranteed by kernel_launch: pre_ho +0S, pre_i +1S, pre_g +2S, pre_f +3S,
// pre_o +4S).
//
// Exchange (proven r0/r4): per phase each wave publishes its 2 results as one
// 16B chunk [v0 v1 seq pad] to the IC; thread t polls chunk (srcWG=t>>3,
// srcWave=t&7) and scatters 2 floats into double-buffered h_sh (A: buf0->buf1,
// B: buf1->buf0) -> 2 barriers/step.
__global__ __launch_bounds__(512, 2) void scan_kernel(
    const float* __restrict__ pre_ho, const float* __restrict__ pre_i,
    const float* __restrict__ pre_g,  const float* __restrict__ pre_f,
    const float* __restrict__ pre_o,
    const float* __restrict__ w_t,  const float* __restrict__ w_ih,
    const float* __restrict__ w_gh, const float* __restrict__ w_fo,
    const float* __restrict__ w_oh,
    float* __restrict__ lines0, float* __restrict__ lines1,
    float* __restrict__ hs, float* __restrict__ cs)
{
  __shared__ __align__(16) float h_sh[2][HDIM];          // 8 KB   [0]=h, [1]=h_o
  __shared__ __align__(16) float pre_sh[5][PBLK][16];    // 20 KB  staged pre_*
  __shared__ __align__(16) float out_sh[2][PBLK][16];    // 8 KB   [0]=hs, [1]=cs

  const int tid  = threadIdx.x;
  const int lane = tid & 63;
  const int w    = tid >> 6;          // wave 0..7
  const int wg   = blockIdx.x;
  const int r0   = wg * RPW + 2 * w;  // this wave's first row
  const long SARR = (long)NROWS * HDIM;

  for (int i = tid; i < HDIM; i += 512) { h_sh[0][i] = 0.f; h_sh[1][i] = 0.f; }

  // weight fragments: Wf[mat][row][m]; mat: 0=w_t 1=w_oh 2=w_ih 3=w_gh 4=w_fo
  // Plain loads (round-0 behavior, measured best).
  vf4 Wf[5][2][4];
  {
    const float* Wp[5] = { w_t, w_oh, w_ih, w_gh, w_fo };
#pragma unroll
    for (int mt = 0; mt < 5; ++mt)
#pragma unroll
      for (int rr = 0; rr < 2; ++rr)
#pragma unroll
        for (int m = 0; m < 4; ++m)
          Wf[mt][rr][m] = *(const vf4*)(Wp[mt] + (long)(r0+rr)*HDIM + m*256 + 4*lane);
  }

  // per-row state in lanes 0,1 of the owning wave
  float cprev = 0.f, oo = 0.f;

  // poll assignment: thread t polls chunk (srcWG = t>>3, srcWave = t&7)
  const long pofs = (long)(tid >> 3) * LINE_W + (long)(tid & 7) * 4;
  const int  dsh  = 2 * tid;          // h_sh scatter base = srcWG*16 + srcWave*2
  const float* pollA = lines0 + pofs;
  const float* pollB = lines1 + pofs;
  float* pubA = lines0 + (long)wg * LINE_W + (long)w * 4;
  float* pubB = lines1 + (long)wg * LINE_W + (long)w * 4;

  __syncthreads();

  for (int n = 0; n < NROWS; ++n) {
    const int ns = n & (PBLK - 1);
    const int tgtA = 2*n + 1, tgtB = 2*n + 2;

    // ==== block boundary: flush previous out block, stage next pre block ====
    if (ns == 0) {
      if (n) {
        const int b0 = n - PBLK;
        const int a = tid >> 8, s = (tid >> 2) & 63, q = (tid & 3) << 2; // 512 chunks
        vf4 v = *(const vf4*)(&out_sh[a][s][q]);
        float* base = a ? cs : hs;
        *(vf4*)(base + (long)(b0 + s)*HDIM + wg*16 + q) = v;
      }
      // stage pre_* block [n, n+PBLK): 5 arrays x 64 steps x 4 vf4 = 1280 chunks
      for (int c = tid; c < 5*PBLK*4; c += 512) {
        const int a = c >> 8, s = (c >> 2) & 63, q = (c & 3) << 2;
        vf4 v = *(const vf4*)(pre_ho + (long)a*SARR + (long)(n + s)*HDIM + wg*16 + q);
        *(vf4*)(&pre_sh[a][s][q]) = v;
      }
      __syncthreads();
    }

    // ======== phase A: h_o = sig(ph + 2*W_t h_prev), o = sig(po + W_oh h_prev) ====
    {
      const int idx = 2*w + (lane & 1);       // LDS broadcast read (2 addrs/wave)
      float ph = pre_sh[0][ns][idx];
      float po = pre_sh[4][ns][idx];
      vf4 h0 = *(const vf4*)(h_sh[0] + 4*lane);
      vf4 h1 = *(const vf4*)(h_sh[0] + 4*lane + 256);
      vf4 h2 = *(const vf4*)(h_sh[0] + 4*lane + 512);
      vf4 h3 = *(const vf4*)(h_sh[0] + 4*lane + 768);
      float t0 = dot4(Wf[0][0][0],h0)+dot4(Wf[0][0][1],h1)+dot4(Wf[0][0][2],h2)+dot4(Wf[0][0][3],h3);
      float t1 = dot4(Wf[0][1][0],h0)+dot4(Wf[0][1][1],h1)+dot4(Wf[0][1][2],h2)+dot4(Wf[0][1][3],h3);
      float o0 = dot4(Wf[1][0][0],h0)+dot4(Wf[1][0][1],h1)+dot4(Wf[1][0][2],h2)+dot4(Wf[1][0][3],h3);
      float o1 = dot4(Wf[1][1][0],h0)+dot4(Wf[1][1][1],h1)+dot4(Wf[1][1][2],h2)+dot4(Wf[1][1][3],h3);
      WRED(t0); WRED(t1); WRED(o0); WRED(o1);
      float hov = 0.f;
      if (lane < 2) {
        float ut = lane ? t1 : t0;
        float uo = lane ? o1 : o0;
        hov = fsig(ph + 2.f * ut);
        oo  = fsig(po + uo);
      }
      float hon = __shfl_xor(hov, 1, 64);     // lane0 gets lane1's value
      if (lane == 0) {
        vf4 d; d.x = hov; d.y = hon; d.z = __int_as_float(tgtA); d.w = 0.f;
        llc_store_f4(pubA, d);
      }
      vf4 d;
      do { d = llc_load_f4(pollA); } while (__float_as_int(d.z) < tgtA);
      *(float2*)(h_sh[1] + dsh) = make_float2(d.x, d.y);   // h_o into buffer 1
      __syncthreads();
    }

    // ======== phase B: gates from h_o; c,h update ========
    {
      const int idx = 2*w + (lane & 1);
      float pi = pre_sh[1][ns][idx];
      float pg = pre_sh[2][ns][idx];
      float pf = pre_sh[3][ns][idx];
      vf4 h0 = *(const vf4*)(h_sh[1] + 4*lane);
      vf4 h1 = *(const vf4*)(h_sh[1] + 4*lane + 256);
      vf4 h2 = *(const vf4*)(h_sh[1] + 4*lane + 512);
      vf4 h3 = *(const vf4*)(h_sh[1] + 4*lane + 768);
      float i0 = dot4(Wf[2][0][0],h0)+dot4(Wf[2][0][1],h1)+dot4(Wf[2][0][2],h2)+dot4(Wf[2][0][3],h3);
      float i1 = dot4(Wf[2][1][0],h0)+dot4(Wf[2][1][1],h1)+dot4(Wf[2][1][2],h2)+dot4(Wf[2][1][3],h3);
      float g0 = dot4(Wf[3][0][0],h0)+dot4(Wf[3][0][1],h1)+dot4(Wf[3][0][2],h2)+dot4(Wf[3][0][3],h3);
      float g1 = dot4(Wf[3][1][0],h0)+dot4(Wf[3][1][1],h1)+dot4(Wf[3][1][2],h2)+dot4(Wf[3][1][3],h3);
      float f0 = dot4(Wf[4][0][0],h0)+dot4(Wf[4][0][1],h1)+dot4(Wf[4][0][2],h2)+dot4(Wf[4][0][3],h3);
      float f1 = dot4(Wf[4][1][0],h0)+dot4(Wf[4][1][1],h1)+dot4(Wf[4][1][2],h2)+dot4(Wf[4][1][3],h3);
      WRED(i0); WRED(i1); WRED(g0); WRED(g1); WRED(f0); WRED(f1);
      float hhv = 0.f, ccv = 0.f;
      if (lane < 2) {
        float ui = lane ? i1 : i0;
        float ug = lane ? g1 : g0;
        float uf = lane ? f1 : f0;
        float ii = fsig(pi + ui);
        float gg = ftanh(pg + ug);
        float ff = fsig(pf + uf);
        ccv = ff * cprev + ii * gg;
        hhv = oo * ftanh(ccv);
        cprev = ccv;
      }
      float hhn = __shfl_xor(hhv, 1, 64);
      if (lane == 0) {                       // publish FIRST: earliest visibility
        vf4 d; d.x = hhv; d.y = hhn; d.z = __int_as_float(tgtB); d.w = 0.f;
        llc_store_f4(pubB, d);
      }
      if (lane < 2) {                        // outputs batched in LDS (flushed per block)
        out_sh[0][ns][2*w + lane] = hhv;
        out_sh[1][ns][2*w + lane] = ccv;
      }
      if (n + 1 < NROWS) {                   // last step: nobody needs h -> skip poll
        vf4 d;
        do { d = llc_load_f4(pollB); } while (__float_as_int(d.z) < tgtB);
        *(float2*)(h_sh[0] + dsh) = make_float2(d.x, d.y); // new h into buffer 0
      }
      __syncthreads();
    }
  }

  // final out block flush [NROWS-PBLK, NROWS)
  {
    const int b0 = NROWS - PBLK;
    const int a = tid >> 8, s = (tid >> 2) & 63, q = (tid & 3) << 2;
    vf4 v = *(const vf4*)(&out_sh[a][s][q]);
    float* base = a ? cs : hs;
    *(vf4*)(base + (long)(b0 + s)*HDIM + wg*16 + q) = v;
  }
}

// ---------- generic accumulating GEMM: C[n,h] += sum_k A[rowmap(n),k]*B[h,k] ----------
__global__ __launch_bounds__(256) void gemm_acc(
    float* __restrict__ C, const float* __restrict__ A, const float* __restrict__ B,
    int K, int shift, int minn)
{
  __shared__ float Asf[16 * 68];
  __shared__ float Bsf[16 * 68];
  const int tid = threadIdx.x;
  const int h0  = blockIdx.x * 64;
  const int n0  = blockIdx.y * 64;
  const int r   = tid >> 2;
  const int kq  = (tid & 3) << 2;
  const int tx  = tid & 15, ty = tid >> 4;

  int arow = n0 + r;
  int src  = arow - shift; if (src < 0) src += NROWS;
  const bool avalid = (arow >= minn);
  const float* Ap = A + (long)src * K + kq;
  const float* Bp = B + (long)(h0 + r) * K + kq;

  vf4 acc0 = {0.f,0.f,0.f,0.f}, acc1 = {0.f,0.f,0.f,0.f};
  vf4 acc2 = {0.f,0.f,0.f,0.f}, acc3 = {0.f,0.f,0.f,0.f};
  const vf4 zero = {0.f,0.f,0.f,0.f};

  for (int k0 = 0; k0 < K; k0 += 16) {
    vf4 av = avalid ? *(const vf4*)(Ap + k0) : zero;
    vf4 bv = *(const vf4*)(Bp + k0);
    __syncthreads();
    Asf[(kq+0)*68 + r] = av.x;  Asf[(kq+1)*68 + r] = av.y;
    Asf[(kq+2)*68 + r] = av.z;  Asf[(kq+3)*68 + r] = av.w;
    Bsf[(kq+0)*68 + r] = bv.x;  Bsf[(kq+1)*68 + r] = bv.y;
    Bsf[(kq+2)*68 + r] = bv.z;  Bsf[(kq+3)*68 + r] = bv.w;
    __syncthreads();
#pragma unroll
    for (int c = 0; c < 16; ++c) {
      vf4 a = *(const vf4*)(Asf + c*68 + (ty << 2));
      vf4 b = *(const vf4*)(Bsf + c*68 + (tx << 2));
      acc0 += a.x * b;
      acc1 += a.y * b;
      acc2 += a.z * b;
      acc3 += a.w * b;
    }
  }
  float* cp = C + (long)(n0 + (ty << 2)) * HDIM + h0 + (tx << 2);
  { vf4 t = *(vf4*)(cp + 0*HDIM); t += acc0; *(vf4*)(cp + 0*HDIM) = t; }
  { vf4 t = *(vf4*)(cp + 1*HDIM); t += acc1; *(vf4*)(cp + 1*HDIM) = t; }
  { vf4 t = *(vf4*)(cp + 2*HDIM); t += acc2; *(vf4*)(cp + 2*HDIM) = t; }
  { vf4 t = *(vf4*)(cp + 3*HDIM); t += acc3; *(vf4*)(cp + 3*HDIM) = t; }
}

__global__ void bias_init(float* __restrict__ out, const float* __restrict__ bias) {
  int i = blockIdx.x * blockDim.x + threadIdx.x;
  vf4 v = {0.f,0.f,0.f,0.f};
  if (bias) { int h = (i << 2) & (HDIM - 1); v = *(const vf4*)(bias + h); }
  *((vf4*)out + i) = v;
}

__global__ void sigmoid_k(float* __restrict__ e) {
  int i = blockIdx.x * blockDim.x + threadIdx.x;
  vf4 v = *((vf4*)e + i);
  v.x = fsig(v.x); v.y = fsig(v.y); v.z = fsig(v.z); v.w = fsig(v.w);
  *((vf4*)e + i) = v;
}

extern "C" void kernel_launch(void* const* d_in, const int* in_sizes, int n_in,
                              void* d_out, int out_size, void* d_ws, size_t ws_size,
                              hipStream_t stream) {
  const float* x    = (const float*)d_in[0];
  const float* xw   = (const float*)d_in[1];
  const float* w_ix = (const float*)d_in[2];
  const float* w_ih = (const float*)d_in[3];
  const float* w_ie = (const float*)d_in[4];
  const float* b_i  = (const float*)d_in[5];
  const float* w_fx = (const float*)d_in[6];
  const float* w_fo = (const float*)d_in[7];
  const float* w_fe = (const float*)d_in[8];
  const float* b_f  = (const float*)d_in[9];
  const float* w_ox = (const float*)d_in[10];
  const float* w_oh = (const float*)d_in[11];
  const float* w_oe = (const float*)d_in[12];
  const float* b_o  = (const float*)d_in[13];
  const float* w_gx = (const float*)d_in[14];
  const float* w_gh = (const float*)d_in[15];
  const float* b_g  = (const float*)d_in[16];
  const float* w_d  = (const float*)d_in[17];
  const float* w_w  = (const float*)d_in[18];
  const float* w_m  = (const float*)d_in[19];
  const float* w_t  = (const float*)d_in[20];
  const float* w_e  = (const float*)d_in[21];
  const float* b_e  = (const float*)d_in[22];

  const long S = (long)NROWS * HDIM;
  float* ws_f   = (float*)d_ws;
  // NOTE: scan_kernel's block staging REQUIRES pre_* contiguous at stride S
  // in this exact order (pre_ho, pre_i, pre_g, pre_f, pre_o).
  float* pre_ho = ws_f + 0*S;
  float* pre_i  = ws_f + 1*S;
  float* pre_g  = ws_f + 2*S;
  float* pre_f  = ws_f + 3*S;
  float* pre_o  = ws_f + 4*S;
  float* e_buf  = ws_f + 5*S;
  float* lines0 = ws_f + 6*S;
  float* lines1 = lines0 + NWG*LINE_W;

  size_t need = (size_t)(6*S + 2*NWG*LINE_W) * sizeof(float);
  if (ws_size < need) {
    fprintf(stderr, "kernel_launch: ws too small (have %zu, need %zu)\n", ws_size, need);
    return;
  }

  dim3 ggrid(HDIM/64, NROWS/64);

  bias_init<<<NROWS, 256, 0, stream>>>(pre_i, b_i);
  bias_init<<<NROWS, 256, 0, stream>>>(pre_g, b_g);
  bias_init<<<NROWS, 256, 0, stream>>>(pre_f, b_f);
  bias_init<<<NROWS, 256, 0, stream>>>(pre_o, b_o);
  bias_init<<<NROWS, 256, 0, stream>>>(e_buf, b_e);
  bias_init<<<NROWS, 256, 0, stream>>>(pre_ho, nullptr);

  gemm_acc<<<ggrid, 256, 0, stream>>>(e_buf, xw, w_e, 64, 0, 0);
  sigmoid_k<<<NROWS, 256, 0, stream>>>(e_buf);

  gemm_acc<<<ggrid, 256, 0, stream>>>(pre_i, x, w_ix, 512, 0, 0);
  gemm_acc<<<ggrid, 256, 0, stream>>>(pre_g, x, w_gx, 512, 0, 0);
  gemm_acc<<<ggrid, 256, 0, stream>>>(pre_f, x, w_fx, 512, 0, 0);
  gemm_acc<<<ggrid, 256, 0, stream>>>(pre_o, x, w_ox, 512, 0, 0);
  gemm_acc<<<ggrid, 256, 0, stream>>>(pre_i, e_buf, w_ie, 1024, 0, 0);
  gemm_acc<<<ggrid, 256, 0, stream>>>(pre_f, e_buf, w_fe, 1024, 0, 0);
  gemm_acc<<<ggrid, 256, 0, stream>>>(pre_o, e_buf, w_oe, 1024, 0, 0);
  gemm_acc<<<ggrid, 256, 0, stream>>>(pre_ho, x, w_d, 512,   96,   96);
  gemm_acc<<<ggrid, 256, 0, stream>>>(pre_ho, x, w_w, 512,  576,  672);
  gemm_acc<<<ggrid, 256, 0, stream>>>(pre_ho, x, w_m, 512, 2784, 2688);

  hipMemsetAsync(lines0, 0, 2 * NWG * LINE_W * sizeof(float), stream);

  float* hs = (float*)d_out;
  float* cs = hs + S;
  scan_kernel<<<NWG, 512, 0, stream>>>(pre_ho, pre_i, pre_g, pre_f, pre_o,
                                       w_t, w_ih, w_gh, w_fo, w_oh,
                                       lines0, lines1, hs, cs);
}

// Round 6
// 39184.872 us; speedup vs baseline: 1.7262x; 1.4179x over previous
//
#include <hip/hip_runtime.h>
#include <cstdio>

#define NROWS 8640      // D*T sequential steps
#define HDIM  1024
#define NWG   64        // persistent workgroups (1 per CU, 64 << 256 CUs -> co-resident)
#define RPW   16        // rows per WG
#define LINE_W 32       // floats per WG per publish buffer (8 chunks x 16B = one 128B line)

typedef float vf4 __attribute__((ext_vector_type(4)));

__device__ __forceinline__ float fsig(float x)  { return 1.f / (1.f + __expf(-x)); }
__device__ __forceinline__ float ftanh(float x) { return 2.f / (1.f + __expf(-2.f * x)) - 1.f; }

// LLC-coherent 16B ops (sc0 sc1: bypass non-coherent per-XCD L1/L2, hit Infinity Cache)
// SAFETY: load + s_waitcnt vmcnt(0) in ONE asm block -> no load outlives its variable.
__device__ __forceinline__ vf4 llc_load_f4(const float* p) {
  vf4 v;
  asm volatile("global_load_dwordx4 %0, %1, off sc0 sc1\n\ts_waitcnt vmcnt(0)"
               : "=v"(v) : "v"(p) : "memory");
  return v;
}
__device__ __forceinline__ void llc_store_f4(float* p, vf4 v) {
  asm volatile("global_store_dwordx4 %0, %1, off sc0 sc1" :: "v"(p), "v"(v) : "memory");
}

__device__ __forceinline__ float dot4(vf4 a, vf4 b) {
  return a.x*b.x + a.y*b.y + a.z*b.z + a.w*b.w;
}

// full-wave butterfly sum (xor-only: measured 0 bank conflicts in round 1)
#define WRED(x) { x += __shfl_xor(x,32,64); x += __shfl_xor(x,16,64); \
                  x += __shfl_xor(x, 8,64); x += __shfl_xor(x, 4,64); \
                  x += __shfl_xor(x, 2,64); x += __shfl_xor(x, 1,64); }

// 64 WGs x 512 threads (8 waves). WG g owns rows [16g,16g+16); wave w owns rows
// 16g+2w, 16g+2w+1 of all 5 matrices, weights in VGPRs (lane l covers h-columns
// {4l..4l+3} + 256m, m=0..3). Per phase each wave publishes its 2 results as one
// 16B chunk [v0 v1 seq pad]; every thread polls exactly one (srcWG,srcWave) chunk
// and scatters 2 floats into LDS h_sh. Seq-in-chunk => one LLC RTT per phase.
//
// R6 deltas vs the proven R0 structure (46.2ms fast-mode), nothing else changed:
//  1. phase A publishes h_o BEFORE computing the o-gate dots (oo isn't needed
//     until phase B) -> o-dots+WRED hide under IC propagation.
//  2. phase B publishes h BEFORE the hs/cs output stores.
//  3. s_sleep(1) between failed poll checks: 32K threads spinning sc1 loads at
//     RTT rate congest the fabric ahead of the publish stores themselves;
//     sleeping ~64cy cuts spin issue rate ~3x (targets the 1.6x slow-mode
//     outliers seen in EVERY round).
__global__ __launch_bounds__(512, 2) void scan_kernel(
    const float* __restrict__ pre_ho, const float* __restrict__ pre_i,
    const float* __restrict__ pre_g,  const float* __restrict__ pre_f,
    const float* __restrict__ pre_o,
    const float* __restrict__ w_t,  const float* __restrict__ w_ih,
    const float* __restrict__ w_gh, const float* __restrict__ w_fo,
    const float* __restrict__ w_oh,
    float* __restrict__ lines0, float* __restrict__ lines1,
    float* __restrict__ hs, float* __restrict__ cs)
{
  __shared__ float h_sh[HDIM];

  const int tid  = threadIdx.x;
  const int lane = tid & 63;
  const int w    = tid >> 6;          // wave 0..7
  const int wg   = blockIdx.x;
  const int r0   = wg * RPW + 2 * w;  // this wave's first row
  const int myrow = r0 + lane;        // valid for lane<2

  for (int i = tid; i < HDIM; i += 512) h_sh[i] = 0.f;

  // weight fragments: Wf[mat][row][m]; mat: 0=w_t 1=w_oh 2=w_ih 3=w_gh 4=w_fo
  vf4 Wf[5][2][4];
  {
    const float* Wp[5] = { w_t, w_oh, w_ih, w_gh, w_fo };
#pragma unroll
    for (int mt = 0; mt < 5; ++mt)
#pragma unroll
      for (int rr = 0; rr < 2; ++rr)
#pragma unroll
        for (int m = 0; m < 4; ++m)
          Wf[mt][rr][m] = *(const vf4*)(Wp[mt] + (long)(r0+rr)*HDIM + m*256 + 4*lane);
  }

  // per-row state in lanes 0,1 of the owning wave
  float cprev = 0.f, oo = 0.f;
  float ph = 0.f, po = 0.f, pi = 0.f, pg = 0.f, pf = 0.f;
  if (lane < 2) {
    ph = pre_ho[myrow]; po = pre_o[myrow];
    pi = pre_i[myrow];  pg = pre_g[myrow]; pf = pre_f[myrow];
  }

  // poll assignment: thread t polls chunk (srcWG = t>>3, srcWave = t&7)
  const long pofs = (long)(tid >> 3) * LINE_W + (long)(tid & 7) * 4;
  const int  dsh  = 2 * tid;          // h_sh scatter base = srcWG*16 + srcWave*2
  const float* pollA = lines0 + pofs;
  const float* pollB = lines1 + pofs;
  float* pubA = lines0 + (long)wg * LINE_W + (long)w * 4;
  float* pubB = lines1 + (long)wg * LINE_W + (long)w * 4;

  __syncthreads();

  for (int n = 0; n < NROWS; ++n) {
    const int tgtA = 2*n + 1, tgtB = 2*n + 2;

    // ======== phase A: h_o = sig(ph + 2*W_t h_prev), o = sig(po + W_oh h_prev) ====
    {
      vf4 h0 = *(const vf4*)(h_sh + 4*lane);
      vf4 h1 = *(const vf4*)(h_sh + 4*lane + 256);
      vf4 h2 = *(const vf4*)(h_sh + 4*lane + 512);
      vf4 h3 = *(const vf4*)(h_sh + 4*lane + 768);
      float t0 = dot4(Wf[0][0][0],h0)+dot4(Wf[0][0][1],h1)+dot4(Wf[0][0][2],h2)+dot4(Wf[0][0][3],h3);
      float t1 = dot4(Wf[0][1][0],h0)+dot4(Wf[0][1][1],h1)+dot4(Wf[0][1][2],h2)+dot4(Wf[0][1][3],h3);
      WRED(t0); WRED(t1);
      float hov = 0.f;
      if (lane < 2) {
        float ut = lane ? t1 : t0;
        hov = fsig(ph + 2.f * ut);
      }
      float hon = __shfl_xor(hov, 1, 64);   // lane0 gets lane1's value
      if (lane == 0) {                      // publish ASAP: 63 WGs wait on this
        vf4 d; d.x = hov; d.y = hon; d.z = __int_as_float(tgtA); d.w = 0.f;
        llc_store_f4(pubA, d);
      }
      // o-gate dots overlapped with IC propagation (oo not needed until phase B)
      float o0 = dot4(Wf[1][0][0],h0)+dot4(Wf[1][0][1],h1)+dot4(Wf[1][0][2],h2)+dot4(Wf[1][0][3],h3);
      float o1 = dot4(Wf[1][1][0],h0)+dot4(Wf[1][1][1],h1)+dot4(Wf[1][1][2],h2)+dot4(Wf[1][1][3],h3);
      WRED(o0); WRED(o1);
      if (lane < 2) {
        float uo = lane ? o1 : o0;
        oo = fsig(po + uo);
      }
    }
    __syncthreads();                         // all h_prev reads retired
    {
      vf4 d = llc_load_f4(pollA);
      while (__float_as_int(d.z) < tgtA) {
        __builtin_amdgcn_s_sleep(1);         // back off: don't congest the fabric
        d = llc_load_f4(pollA);
      }
      *(float2*)(h_sh + dsh) = make_float2(d.x, d.y);
    }
    __syncthreads();                         // h_sh now holds h_o

    // ======== phase B: gates from h_o; c,h update ========
    {
      // prefetch next step's pre_* early (overlaps dot compute)
      float ph2 = 0.f, po2 = 0.f, pi2 = 0.f, pg2 = 0.f, pf2 = 0.f;
      if (lane < 2 && n + 1 < NROWS) {
        long o2 = (long)(n+1)*HDIM + myrow;
        ph2 = pre_ho[o2]; po2 = pre_o[o2];
        pi2 = pre_i[o2];  pg2 = pre_g[o2]; pf2 = pre_f[o2];
      }
      vf4 h0 = *(const vf4*)(h_sh + 4*lane);
      vf4 h1 = *(const vf4*)(h_sh + 4*lane + 256);
      vf4 h2 = *(const vf4*)(h_sh + 4*lane + 512);
      vf4 h3 = *(const vf4*)(h_sh + 4*lane + 768);
      float i0 = dot4(Wf[2][0][0],h0)+dot4(Wf[2][0][1],h1)+dot4(Wf[2][0][2],h2)+dot4(Wf[2][0][3],h3);
      float i1 = dot4(Wf[2][1][0],h0)+dot4(Wf[2][1][1],h1)+dot4(Wf[2][1][2],h2)+dot4(Wf[2][1][3],h3);
      float g0 = dot4(Wf[3][0][0],h0)+dot4(Wf[3][0][1],h1)+dot4(Wf[3][0][2],h2)+dot4(Wf[3][0][3],h3);
      float g1 = dot4(Wf[3][1][0],h0)+dot4(Wf[3][1][1],h1)+dot4(Wf[3][1][2],h2)+dot4(Wf[3][1][3],h3);
      float f0 = dot4(Wf[4][0][0],h0)+dot4(Wf[4][0][1],h1)+dot4(Wf[4][0][2],h2)+dot4(Wf[4][0][3],h3);
      float f1 = dot4(Wf[4][1][0],h0)+dot4(Wf[4][1][1],h1)+dot4(Wf[4][1][2],h2)+dot4(Wf[4][1][3],h3);
      WRED(i0); WRED(i1); WRED(g0); WRED(g1); WRED(f0); WRED(f1);
      float hhv = 0.f, ccv = 0.f;
      if (lane < 2) {
        float ui = lane ? i1 : i0;
        float ug = lane ? g1 : g0;
        float uf = lane ? f1 : f0;
        float ii = fsig(pi + ui);
        float gg = ftanh(pg + ug);
        float ff = fsig(pf + uf);
        ccv = ff * cprev + ii * gg;
        hhv = oo * ftanh(ccv);
        cprev = ccv;
      }
      float hhn = __shfl_xor(hhv, 1, 64);
      if (lane == 0) {                       // publish FIRST: earliest visibility
        vf4 d; d.x = hhv; d.y = hhn; d.z = __int_as_float(tgtB); d.w = 0.f;
        llc_store_f4(pubB, d);
      }
      if (lane < 2) {                        // private output stores after publish
        hs[(long)n*HDIM + myrow] = hhv;
        cs[(long)n*HDIM + myrow] = ccv;
      }
      ph = ph2; po = po2; pi = pi2; pg = pg2; pf = pf2;
    }
    __syncthreads();                         // all h_o reads retired
    {
      vf4 d = llc_load_f4(pollB);
      while (__float_as_int(d.z) < tgtB) {
        __builtin_amdgcn_s_sleep(1);
        d = llc_load_f4(pollB);
      }
      *(float2*)(h_sh + dsh) = make_float2(d.x, d.y);
    }
    __syncthreads();                         // h_sh now holds new h
  }
}

// ---------- generic accumulating GEMM: C[n,h] += sum_k A[rowmap(n),k]*B[h,k] ----------
__global__ __launch_bounds__(256) void gemm_acc(
    float* __restrict__ C, const float* __restrict__ A, const float* __restrict__ B,
    int K, int shift, int minn)
{
  __shared__ float Asf[16 * 68];
  __shared__ float Bsf[16 * 68];
  const int tid = threadIdx.x;
  const int h0  = blockIdx.x * 64;
  const int n0  = blockIdx.y * 64;
  const int r   = tid >> 2;
  const int kq  = (tid & 3) << 2;
  const int tx  = tid & 15, ty = tid >> 4;

  int arow = n0 + r;
  int src  = arow - shift; if (src < 0) src += NROWS;
  const bool avalid = (arow >= minn);
  const float* Ap = A + (long)src * K + kq;
  const float* Bp = B + (long)(h0 + r) * K + kq;

  vf4 acc0 = {0.f,0.f,0.f,0.f}, acc1 = {0.f,0.f,0.f,0.f};
  vf4 acc2 = {0.f,0.f,0.f,0.f}, acc3 = {0.f,0.f,0.f,0.f};
  const vf4 zero = {0.f,0.f,0.f,0.f};

  for (int k0 = 0; k0 < K; k0 += 16) {
    vf4 av = avalid ? *(const vf4*)(Ap + k0) : zero;
    vf4 bv = *(const vf4*)(Bp + k0);
    __syncthreads();
    Asf[(kq+0)*68 + r] = av.x;  Asf[(kq+1)*68 + r] = av.y;
    Asf[(kq+2)*68 + r] = av.z;  Asf[(kq+3)*68 + r] = av.w;
    Bsf[(kq+0)*68 + r] = bv.x;  Bsf[(kq+1)*68 + r] = bv.y;
    Bsf[(kq+2)*68 + r] = bv.z;  Bsf[(kq+3)*68 + r] = bv.w;
    __syncthreads();
#pragma unroll
    for (int c = 0; c < 16; ++c) {
      vf4 a = *(const vf4*)(Asf + c*68 + (ty << 2));
      vf4 b = *(const vf4*)(Bsf + c*68 + (tx << 2));
      acc0 += a.x * b;
      acc1 += a.y * b;
      acc2 += a.z * b;
      acc3 += a.w * b;
    }
  }
  float* cp = C + (long)(n0 + (ty << 2)) * HDIM + h0 + (tx << 2);
  { vf4 t = *(vf4*)(cp + 0*HDIM); t += acc0; *(vf4*)(cp + 0*HDIM) = t; }
  { vf4 t = *(vf4*)(cp + 1*HDIM); t += acc1; *(vf4*)(cp + 1*HDIM) = t; }
  { vf4 t = *(vf4*)(cp + 2*HDIM); t += acc2; *(vf4*)(cp + 2*HDIM) = t; }
  { vf4 t = *(vf4*)(cp + 3*HDIM); t += acc3; *(vf4*)(cp + 3*HDIM) = t; }
}

__global__ void bias_init(float* __restrict__ out, const float* __restrict__ bias) {
  int i = blockIdx.x * blockDim.x + threadIdx.x;
  vf4 v = {0.f,0.f,0.f,0.f};
  if (bias) { int h = (i << 2) & (HDIM - 1); v = *(const vf4*)(bias + h); }
  *((vf4*)out + i) = v;
}

__global__ void sigmoid_k(float* __restrict__ e) {
  int i = blockIdx.x * blockDim.x + threadIdx.x;
  vf4 v = *((vf4*)e + i);
  v.x = fsig(v.x); v.y = fsig(v.y); v.z = fsig(v.z); v.w = fsig(v.w);
  *((vf4*)e + i) = v;
}

extern "C" void kernel_launch(void* const* d_in, const int* in_sizes, int n_in,
                              void* d_out, int out_size, void* d_ws, size_t ws_size,
                              hipStream_t stream) {
  const float* x    = (const float*)d_in[0];
  const float* xw   = (const float*)d_in[1];
  const float* w_ix = (const float*)d_in[2];
  const float* w_ih = (const float*)d_in[3];
  const float* w_ie = (const float*)d_in[4];
  const float* b_i  = (const float*)d_in[5];
  const float* w_fx = (const float*)d_in[6];
  const float* w_fo = (const float*)d_in[7];
  const float* w_fe = (const float*)d_in[8];
  const float* b_f  = (const float*)d_in[9];
  const float* w_ox = (const float*)d_in[10];
  const float* w_oh = (const float*)d_in[11];
  const float* w_oe = (const float*)d_in[12];
  const float* b_o  = (const float*)d_in[13];
  const float* w_gx = (const float*)d_in[14];
  const float* w_gh = (const float*)d_in[15];
  const float* b_g  = (const float*)d_in[16];
  const float* w_d  = (const float*)d_in[17];
  const float* w_w  = (const float*)d_in[18];
  const float* w_m  = (const float*)d_in[19];
  const float* w_t  = (const float*)d_in[20];
  const float* w_e  = (const float*)d_in[21];
  const float* b_e  = (const float*)d_in[22];

  const long S = (long)NROWS * HDIM;
  float* ws_f   = (float*)d_ws;
  float* pre_ho = ws_f + 0*S;
  float* pre_i  = ws_f + 1*S;
  float* pre_g  = ws_f + 2*S;
  float* pre_f  = ws_f + 3*S;
  float* pre_o  = ws_f + 4*S;
  float* e_buf  = ws_f + 5*S;
  float* lines0 = ws_f + 6*S;
  float* lines1 = lines0 + NWG*LINE_W;

  size_t need = (size_t)(6*S + 2*NWG*LINE_W) * sizeof(float);
  if (ws_size < need) {
    fprintf(stderr, "kernel_launch: ws too small (have %zu, need %zu)\n", ws_size, need);
    return;
  }

  dim3 ggrid(HDIM/64, NROWS/64);

  bias_init<<<NROWS, 256, 0, stream>>>(pre_i, b_i);
  bias_init<<<NROWS, 256, 0, stream>>>(pre_g, b_g);
  bias_init<<<NROWS, 256, 0, stream>>>(pre_f, b_f);
  bias_init<<<NROWS, 256, 0, stream>>>(pre_o, b_o);
  bias_init<<<NROWS, 256, 0, stream>>>(e_buf, b_e);
  bias_init<<<NROWS, 256, 0, stream>>>(pre_ho, nullptr);

  gemm_acc<<<ggrid, 256, 0, stream>>>(e_buf, xw, w_e, 64, 0, 0);
  sigmoid_k<<<NROWS, 256, 0, stream>>>(e_buf);

  gemm_acc<<<ggrid, 256, 0, stream>>>(pre_i, x, w_ix, 512, 0, 0);
  gemm_acc<<<ggrid, 256, 0, stream>>>(pre_g, x, w_gx, 512, 0, 0);
  gemm_acc<<<ggrid, 256, 0, stream>>>(pre_f, x, w_fx, 512, 0, 0);
  gemm_acc<<<ggrid, 256, 0, stream>>>(pre_o, x, w_ox, 512, 0, 0);
  gemm_acc<<<ggrid, 256, 0, stream>>>(pre_i, e_buf, w_ie, 1024, 0, 0);
  gemm_acc<<<ggrid, 256, 0, stream>>>(pre_f, e_buf, w_fe, 1024, 0, 0);
  gemm_acc<<<ggrid, 256, 0, stream>>>(pre_o, e_buf, w_oe, 1024, 0, 0);
  gemm_acc<<<ggrid, 256, 0, stream>>>(pre_ho, x, w_d, 512,   96,   96);
  gemm_acc<<<ggrid, 256, 0, stream>>>(pre_ho, x, w_w, 512,  576,  672);
  gemm_acc<<<ggrid, 256, 0, stream>>>(pre_ho, x, w_m, 512, 2784, 2688);

  hipMemsetAsync(lines0, 0, 2 * NWG * LINE_W * sizeof(float), stream);

  float* hs = (float*)d_out;
  float* cs = hs + S;
  scan_kernel<<<NWG, 512, 0, stream>>>(pre_ho, pre_i, pre_g, pre_f, pre_o,
                                       w_t, w_ih, w_gh, w_fo, w_oh,
                                       lines0, lines1, hs, cs);
}